// Round 3
// baseline (279.606 us; speedup 1.0000x reference)
//
#include <hip/hip_runtime.h>

// LightGCN layer: out[v] = sum_{(u->v)} w * x[u], N=100K, E=1.6M, D=128, fp32.
//
// R11: R8-R10 established gather's floor: FETCH ~350-375MB is structural
// (each of 8 XCDs touches ~86% of x's rows once: 8 x 44MB ~ 350MB) and
// ~3.4 TB/s ~ 170 lines/cy is near the LLC random-line rate. Best gather =
// R8's (restored verbatim, ~126us). Remaining fat: front-end ~124us for
// ~40MB logical traffic. Rebuilt:
//   - hist: LDS hist -> global atomicAdd per bucket; LAST block (done-counter)
//     computes the 782-entry prefix in-kernel. Scan kernel + 800KB transposed
//     hist table eliminated.
//   - scatter: stage 3125-edge tile in LDS, counting-sort by bucket, reserve
//     per-bucket runs via one global atomicAdd each, write CSR in SORTED
//     order (contiguous runs) -> kills 1.6M scattered 8B line-RMW stores
//     (~100MB hidden fetch).
//   - gather: R8 structure, beg/end from gbase.
// Dispatches: memset(8KB) -> hist(+prefix) -> scatter -> gather.

constexpr int D_FEAT = 128;
constexpr int NPB = 128;        // nodes per bucket (dst >> 7)
constexpr int NBK_MAX = 1024;
constexpr int HBLK = 256;       // hist block count
constexpr int CTILE = 3136;     // scatter LDS tile capacity (>= tile 3125)
constexpr int CAP = 3072;       // max edges per bucket staged in gather LDS

typedef float v4f __attribute__((ext_vector_type(4)));

// ---------------- fallback (R1) ----------------
__global__ __launch_bounds__(256) void scatter_atomic_kernel(
    const float* __restrict__ x, const float* __restrict__ w,
    const int* __restrict__ src_idx, const int* __restrict__ dst_idx,
    float* __restrict__ out, int n_edges) {
  long long tid = (long long)blockIdx.x * blockDim.x + threadIdx.x;
  int lane = (int)(tid & 31);
  long long e = tid >> 5;
  if (e >= n_edges) return;
  int s = src_idx[e];
  int d = dst_idx[e];
  float wt = w[e];
  float4 v = ((const float4*)(x + (size_t)s * D_FEAT))[lane];
  float* o = out + (size_t)d * D_FEAT + (size_t)lane * 4;
  atomicAdd(o + 0, v.x * wt);
  atomicAdd(o + 1, v.y * wt);
  atomicAdd(o + 2, v.z * wt);
  atomicAdd(o + 3, v.w * wt);
}

// block-wide exclusive scan over blockDim.x threads (multiple of 64, <=512);
// sh holds >= (nwaves+1) ints (declare 9).
__device__ __forceinline__ int block_excl_scan(int v, int* sh, int* total) {
  const int lane = threadIdx.x & 63;
  const int wid = threadIdx.x >> 6;
  const int nw = blockDim.x >> 6;
  int inc = v;
  #pragma unroll
  for (int o = 1; o < 64; o <<= 1) {
    int t = __shfl_up(inc, o, 64);
    if (lane >= o) inc += t;
  }
  if (lane == 63) sh[wid] = inc;
  __syncthreads();
  if (threadIdx.x == 0) {
    int a = 0;
    for (int k = 0; k < nw; ++k) { int t = sh[k]; sh[k] = a; a += t; }
    sh[nw] = a;
  }
  __syncthreads();
  int r = sh[wid] + inc - v;
  if (total) *total = sh[nw];
  __syncthreads();
  return r;
}

// ---------------- phase 1: global bucket hist + in-kernel prefix -----------
// gtot/gcur/done pre-zeroed by memset. Last block to finish computes the
// exclusive prefix into gbase[0..nbk] and initializes gcur = gbase.
__global__ __launch_bounds__(512) void hist_kernel(
    const int* __restrict__ dst, int* __restrict__ gtot,
    int* __restrict__ gcur, int* __restrict__ gbase, int* __restrict__ done,
    int n_edges, int nbk, int tile) {
  __shared__ int h[NBK_MAX];
  __shared__ int sh[9];
  __shared__ int slast;
  const int tid = threadIdx.x;
  const int b = blockIdx.x;
  for (int k = tid; k < nbk; k += 512) h[k] = 0;
  __syncthreads();
  int base = b * tile;
  int lim = min(base + tile, n_edges);
  for (int i = base + tid; i < lim; i += 512)
    atomicAdd(&h[((unsigned)dst[i]) >> 7], 1);
  __syncthreads();
  for (int k = tid; k < nbk; k += 512)
    if (h[k]) atomicAdd(&gtot[k], h[k]);
  __threadfence();
  __syncthreads();
  if (tid == 0)
    slast = (__hip_atomic_fetch_add(done, 1, __ATOMIC_ACQ_REL,
                                    __HIP_MEMORY_SCOPE_AGENT) ==
             (int)gridDim.x - 1);
  __syncthreads();
  if (slast) {
    int carry = 0;
    for (int kb = 0; kb < nbk; kb += 512) {
      int k = kb + tid;
      int v = (k < nbk)
                  ? __hip_atomic_load(&gtot[k], __ATOMIC_RELAXED,
                                      __HIP_MEMORY_SCOPE_AGENT)
                  : 0;
      int tot;
      int ex = block_excl_scan(v, sh, &tot);
      if (k < nbk) { gbase[k] = carry + ex; gcur[k] = carry + ex; }
      carry += tot;
    }
    if (tid == 0) gbase[nbk] = carry;
  }
}

// ---------------- phase 2: sorted scatter (stage + counting-sort in LDS) ---
// Each block stages its tile, sorts by bucket, reserves per-bucket runs with
// one global atomicAdd per non-empty bucket, writes CSR in sorted order
// (contiguous runs -> coalesced stores, no per-8B line RMW).
__global__ __launch_bounds__(512) void scatter_kernel(
    const int* __restrict__ src, const int* __restrict__ dst,
    const float* __restrict__ w, int* __restrict__ gcur,
    uint2* __restrict__ csr, int n_edges, int nbk, int tile) {
  __shared__ uint2 ed[CTILE];              // 25.1 KB staged edges
  __shared__ unsigned short bkt[CTILE];    // 6.3 KB bucket per edge
  __shared__ unsigned int prm[CTILE];      // 12.5 KB (j | k<<12)
  __shared__ int h[NBK_MAX];               // counts
  __shared__ int lb[NBK_MAX];              // local exclusive base
  __shared__ int cur[NBK_MAX];             // placement cursor
  __shared__ int gb[NBK_MAX];              // global run base
  __shared__ int sh[9];

  const int tid = threadIdx.x;
  const int b = blockIdx.x;
  int base = b * tile;
  int lim = min(base + tile, n_edges);
  int cnt = max(lim - base, 0);

  for (int k = tid; k < nbk; k += 512) { h[k] = 0; cur[k] = 0; }
  __syncthreads();
  for (int i = base + tid; i < lim; i += 512) {
    int j = i - base;
    unsigned d = (unsigned)dst[i];
    unsigned k = d >> 7;
    ed[j] = make_uint2((unsigned)src[i] | ((d & 127u) << 20),
                       __float_as_uint(w[i]));
    bkt[j] = (unsigned short)k;
    atomicAdd(&h[k], 1);
  }
  __syncthreads();
  {
    int carry = 0;
    for (int kb = 0; kb < nbk; kb += 512) {
      int k = kb + tid;
      int v = (k < nbk) ? h[k] : 0;
      int tot;
      int ex = block_excl_scan(v, sh, &tot);
      if (k < nbk) {
        lb[k] = carry + ex;
        if (v) gb[k] = atomicAdd(&gcur[k], v);   // reserve global run
      }
      carry += tot;
    }
  }
  __syncthreads();
  for (int j = tid; j < cnt; j += 512) {
    int k = bkt[j];
    int oc = atomicAdd(&cur[k], 1);
    prm[lb[k] + oc] = (unsigned)j | ((unsigned)k << 12);
  }
  __syncthreads();
  for (int p = tid; p < cnt; p += 512) {
    unsigned v = prm[p];
    int j = (int)(v & 0xFFFu);
    int k = (int)(v >> 12);
    csr[gb[k] + (p - lb[k])] = ed[j];
  }
}

// ---------------- phase 3: gather (R8 structure: LDS perm-sort + reg acc) --
__global__ __launch_bounds__(256) void gather_kernel(
    const float* __restrict__ x, const int* __restrict__ gbase,
    const uint2* __restrict__ csr, float* __restrict__ out, int n_nodes) {
  __shared__ uint2 eds[CAP];            // 24 KB staged edges
  __shared__ unsigned short perm[CAP];  // 6 KB sorted order
  __shared__ int loff[NPB + 1];
  __shared__ int lcur[NPB];
  __shared__ int sh[9];

  const int b = blockIdx.x;
  const int tid = threadIdx.x;
  const int beg = gbase[b];
  const int end = gbase[b + 1];
  const int cnt = end - beg;
  const int nbase = b * NPB;

  const int wv = tid >> 6;
  const int lane = tid & 63;
  const int f = lane & 31;
  const int half = lane >> 5;
  const float4* X = (const float4*)x;

  if (cnt <= CAP) {
    // stage + local hist
    if (tid < NPB) lcur[tid] = 0;
    __syncthreads();
    for (int i = tid; i < cnt; i += 256) {
      uint2 e = csr[beg + i];
      eds[i] = e;
      atomicAdd(&lcur[e.x >> 20], 1);
    }
    __syncthreads();
    // scan 128 counters -> loff, reset lcur as cursor
    {
      int v = (tid < NPB) ? lcur[tid] : 0;
      int ex = block_excl_scan(v, sh, nullptr);
      __syncthreads();
      if (tid < NPB) { loff[tid] = ex; lcur[tid] = 0; }
      if (tid == 0) loff[NPB] = cnt;
    }
    __syncthreads();
    // build perm (counting-sort placement)
    for (int i = tid; i < cnt; i += 256) {
      int dl = eds[i].x >> 20;
      int pos = loff[dl] + atomicAdd(&lcur[dl], 1);
      perm[pos] = (unsigned short)i;
    }
    __syncthreads();

    // register-accumulate per node (1 wave/node, 2 halves x unroll4)
    for (int n = wv; n < NPB; n += 4) {
      int node = nbase + n;
      if (node >= n_nodes) break;
      int jb = loff[n];
      int je = loff[n + 1];
      float4 a0 = make_float4(0.f, 0.f, 0.f, 0.f);
      float4 a1 = make_float4(0.f, 0.f, 0.f, 0.f);
      float4 a2 = make_float4(0.f, 0.f, 0.f, 0.f);
      float4 a3 = make_float4(0.f, 0.f, 0.f, 0.f);
      int j = jb + half;
      for (; j + 6 < je; j += 8) {
        uint2 e0 = eds[perm[j]];
        uint2 e1 = eds[perm[j + 2]];
        uint2 e2 = eds[perm[j + 4]];
        uint2 e3 = eds[perm[j + 6]];
        float4 v0 = X[(size_t)(e0.x & 0xFFFFFu) * 32 + f];
        float4 v1 = X[(size_t)(e1.x & 0xFFFFFu) * 32 + f];
        float4 v2 = X[(size_t)(e2.x & 0xFFFFFu) * 32 + f];
        float4 v3 = X[(size_t)(e3.x & 0xFFFFFu) * 32 + f];
        float w0 = __uint_as_float(e0.y);
        float w1 = __uint_as_float(e1.y);
        float w2 = __uint_as_float(e2.y);
        float w3 = __uint_as_float(e3.y);
        a0.x += w0 * v0.x; a0.y += w0 * v0.y; a0.z += w0 * v0.z; a0.w += w0 * v0.w;
        a1.x += w1 * v1.x; a1.y += w1 * v1.y; a1.z += w1 * v1.z; a1.w += w1 * v1.w;
        a2.x += w2 * v2.x; a2.y += w2 * v2.y; a2.z += w2 * v2.z; a2.w += w2 * v2.w;
        a3.x += w3 * v3.x; a3.y += w3 * v3.y; a3.z += w3 * v3.z; a3.w += w3 * v3.w;
      }
      for (; j < je; j += 2) {
        uint2 e0 = eds[perm[j]];
        float4 v0 = X[(size_t)(e0.x & 0xFFFFFu) * 32 + f];
        float w0 = __uint_as_float(e0.y);
        a0.x += w0 * v0.x; a0.y += w0 * v0.y; a0.z += w0 * v0.z; a0.w += w0 * v0.w;
      }
      a0.x += a1.x + a2.x + a3.x;
      a0.y += a1.y + a2.y + a3.y;
      a0.z += a1.z + a2.z + a3.z;
      a0.w += a1.w + a2.w + a3.w;
      a0.x += __shfl_xor(a0.x, 32, 64);
      a0.y += __shfl_xor(a0.y, 32, 64);
      a0.z += __shfl_xor(a0.z, 32, 64);
      a0.w += __shfl_xor(a0.w, 32, 64);
      if (half == 0) {
        v4f val = {a0.x, a0.y, a0.z, a0.w};
        __builtin_nontemporal_store(val, (v4f*)out + (size_t)node * 32 + f);
      }
    }
  } else {
    // safety net (statistically unreachable): per-node scan of the bucket
    for (int n = wv; n < NPB; n += 4) {
      int node = nbase + n;
      if (node >= n_nodes) break;
      float4 a0 = make_float4(0.f, 0.f, 0.f, 0.f);
      for (int j = half; j < cnt; j += 2) {
        uint2 e = csr[beg + j];
        if ((int)(e.x >> 20) == n) {
          float4 v = X[(size_t)(e.x & 0xFFFFFu) * 32 + f];
          float wt = __uint_as_float(e.y);
          a0.x += wt * v.x; a0.y += wt * v.y; a0.z += wt * v.z; a0.w += wt * v.w;
        }
      }
      a0.x += __shfl_xor(a0.x, 32, 64);
      a0.y += __shfl_xor(a0.y, 32, 64);
      a0.z += __shfl_xor(a0.z, 32, 64);
      a0.w += __shfl_xor(a0.w, 32, 64);
      if (half == 0) {
        v4f val = {a0.x, a0.y, a0.z, a0.w};
        __builtin_nontemporal_store(val, (v4f*)out + (size_t)node * 32 + f);
      }
    }
  }
}

extern "C" void kernel_launch(void* const* d_in, const int* in_sizes, int n_in,
                              void* d_out, int out_size, void* d_ws, size_t ws_size,
                              hipStream_t stream) {
  const float* x  = (const float*)d_in[0];
  const float* w  = (const float*)d_in[1];
  const int* eidx = (const int*)d_in[2];

  int n_edges = in_sizes[1];           // E
  int n_nodes = out_size / D_FEAT;     // N
  const int* src = eidx;
  const int* dst = eidx + n_edges;
  float* out = (float*)d_out;

  const int nbk = (n_nodes + NPB - 1) / NPB;       // buckets (782 @100K)
  const int htile = (n_edges + HBLK - 1) / HBLK;   // edges per hist block
  const int cblk = (n_edges + CTILE - 11 - 1) / (CTILE - 11); // tile<=3125
  const int ctile = cblk > 0 ? (n_edges + cblk - 1) / cblk : 0;

  // ws layout (ints): gtot[1024] | gcur[1024] | done[4] | gbase[1028] | csr
  const size_t ctrl_ints = 1024 + 1024 + 4 + 1028;  // 3080 ints = 12320 B
  size_t need = ctrl_ints * 4 + (size_t)n_edges * 8;
  if (n_edges <= 0) {
    hipMemsetAsync(d_out, 0, (size_t)out_size * sizeof(float), stream);
    return;
  }
  if (ws_size < need || nbk > NBK_MAX || n_nodes >= (1 << 20) ||
      ctile > CTILE) {
    hipMemsetAsync(d_out, 0, (size_t)out_size * sizeof(float), stream);
    long long total_threads = (long long)n_edges * 32;
    long long grid = (total_threads + 255) / 256;
    scatter_atomic_kernel<<<(dim3)(unsigned)grid, 256, 0, stream>>>(
        x, w, src, dst, out, n_edges);
    return;
  }

  int* gtot = (int*)d_ws;               // 1024
  int* gcur = gtot + 1024;              // 1024
  int* done = gcur + 1024;              // 4
  int* gbase = done + 4;                // 1028 (nbk+1 used)
  uint2* csr = (uint2*)(gbase + 1028);  // E

  // zero gtot, gcur, done (8208 B)
  hipMemsetAsync(gtot, 0, (1024 + 1024 + 4) * sizeof(int), stream);

  hist_kernel<<<HBLK, 512, 0, stream>>>(dst, gtot, gcur, gbase, done,
                                        n_edges, nbk, htile);
  scatter_kernel<<<cblk, 512, 0, stream>>>(src, dst, w, gcur, csr,
                                           n_edges, nbk, ctile);
  gather_kernel<<<nbk, 256, 0, stream>>>(x, gbase, csr, out, n_nodes);
}

// Round 4
// 254.299 us; speedup vs baseline: 1.0995x; 1.0995x over previous
//
#include <hip/hip_runtime.h>
#include <math.h>

// LightGCN layer: out[v] = sum_{(u->v)} w * x[u], N=100K, E=1.6M, D=128, fp32.
//
// R12: R11 post-mortem — gather reproduced at 126.5us (3.43 TB/s, FETCH
// 375MB, occ 30%); the rebuilt front-end REGRESSED (153us vs R10's 123):
// sorted scatter's 60KB LDS (2 blk/CU) + 5 LDS passes + memset cost more
// than the scan they replaced. Two fixes:
//   - gather occupancy WITHOUT ILP loss (R9's mistake): NPB 128->64 ->
//     1563 blocks, CAP 1536, LDS 16KB -> ~6 blk/CU x 4 waves = ~24 waves/CU
//     (vs 12), same 44-VGPR 8-rows-in-flight loop. Clean latency-vs-LLC test.
//   - front-end: fixed-offset segments (bucket*CAPB) kill hist+scan+prefix.
//     scatter does LDS tile-hist, reserves runs via 1 global atomicAdd per
//     non-empty bucket, places edges; gather reads cnt = gcur[b]-b*CAPB.
//     CAPB sized from ws_size at launch; exact-CSR path (hist+prefix) kept
//     as fallback when ws is small; overflow -> raw-scan branch (P~1e-6).
// Dispatches (segment path): init(2us) -> scatter -> gather.

constexpr int D_FEAT = 128;
constexpr int NPB = 64;         // nodes per bucket (dst >> 6)
constexpr int LOG_NPB = 6;
constexpr int NBK_MAX = 2048;
constexpr int HBLK = 256;       // hist block count (exact path)
constexpr int SCB = 256;        // scatter block count
constexpr int CAP = 1536;       // max edges per bucket staged in gather LDS

typedef float v4f __attribute__((ext_vector_type(4)));

// ---------------- fallback (R1) ----------------
__global__ __launch_bounds__(256) void scatter_atomic_kernel(
    const float* __restrict__ x, const float* __restrict__ w,
    const int* __restrict__ src_idx, const int* __restrict__ dst_idx,
    float* __restrict__ out, int n_edges) {
  long long tid = (long long)blockIdx.x * blockDim.x + threadIdx.x;
  int lane = (int)(tid & 31);
  long long e = tid >> 5;
  if (e >= n_edges) return;
  int s = src_idx[e];
  int d = dst_idx[e];
  float wt = w[e];
  float4 v = ((const float4*)(x + (size_t)s * D_FEAT))[lane];
  float* o = out + (size_t)d * D_FEAT + (size_t)lane * 4;
  atomicAdd(o + 0, v.x * wt);
  atomicAdd(o + 1, v.y * wt);
  atomicAdd(o + 2, v.z * wt);
  atomicAdd(o + 3, v.w * wt);
}

// block-wide exclusive scan over blockDim.x threads (multiple of 64, <=512);
// sh holds >= (nwaves+1) ints (declare 9).
__device__ __forceinline__ int block_excl_scan(int v, int* sh, int* total) {
  const int lane = threadIdx.x & 63;
  const int wid = threadIdx.x >> 6;
  const int nw = blockDim.x >> 6;
  int inc = v;
  #pragma unroll
  for (int o = 1; o < 64; o <<= 1) {
    int t = __shfl_up(inc, o, 64);
    if (lane >= o) inc += t;
  }
  if (lane == 63) sh[wid] = inc;
  __syncthreads();
  if (threadIdx.x == 0) {
    int a = 0;
    for (int k = 0; k < nw; ++k) { int t = sh[k]; sh[k] = a; a += t; }
    sh[nw] = a;
  }
  __syncthreads();
  int r = sh[wid] + inc - v;
  if (total) *total = sh[nw];
  __syncthreads();
  return r;
}

// ---------------- exact path phase 1: global hist + in-kernel prefix -------
// gtot/gcur/done pre-zeroed by memset. Last block computes the exclusive
// prefix into gbase[0..nbk] and initializes gcur = gbase.
__global__ __launch_bounds__(512) void hist_kernel(
    const int* __restrict__ dst, int* __restrict__ gtot,
    int* __restrict__ gcur, int* __restrict__ gbase, int* __restrict__ done,
    int n_edges, int nbk, int tile) {
  __shared__ int h[NBK_MAX];
  __shared__ int sh[9];
  __shared__ int slast;
  const int tid = threadIdx.x;
  const int b = blockIdx.x;
  for (int k = tid; k < nbk; k += 512) h[k] = 0;
  __syncthreads();
  int base = b * tile;
  int lim = min(base + tile, n_edges);
  for (int i = base + tid; i < lim; i += 512)
    atomicAdd(&h[((unsigned)dst[i]) >> LOG_NPB], 1);
  __syncthreads();
  for (int k = tid; k < nbk; k += 512)
    if (h[k]) atomicAdd(&gtot[k], h[k]);
  __threadfence();
  __syncthreads();
  if (tid == 0)
    slast = (__hip_atomic_fetch_add(done, 1, __ATOMIC_ACQ_REL,
                                    __HIP_MEMORY_SCOPE_AGENT) ==
             (int)gridDim.x - 1);
  __syncthreads();
  if (slast) {
    int carry = 0;
    for (int kb = 0; kb < nbk; kb += 512) {
      int k = kb + tid;
      int v = (k < nbk)
                  ? __hip_atomic_load(&gtot[k], __ATOMIC_RELAXED,
                                      __HIP_MEMORY_SCOPE_AGENT)
                  : 0;
      int tot;
      int ex = block_excl_scan(v, sh, &tot);
      if (k < nbk) { gbase[k] = carry + ex; gcur[k] = carry + ex; }
      carry += tot;
    }
    if (tid == 0) gbase[nbk] = carry;
  }
}

// ---------------- segment path init: gcur[k] = k*capb ----------------------
__global__ __launch_bounds__(256) void init_seg_kernel(int* __restrict__ gcur,
                                                       int nbk, int capb) {
  int k = blockIdx.x * 256 + threadIdx.x;
  if (k < nbk) gcur[k] = k * capb;
}

// ---------------- phase 2: scatter (LDS tile-hist + run reservation) -------
// pass1: LDS hist of the tile; reserve per-bucket runs with ONE global
// atomicAdd per non-empty bucket; pass2: re-read (L2-warm) and place via LDS
// cursors. Per-(block,bucket) runs are contiguous (~4 edges = 32B).
// capb != 0 => segment mode: stores beyond a segment's capacity are dropped
// (detected by gather via cnt > capb -> raw-scan fallback).
__global__ __launch_bounds__(512) void scatter_kernel(
    const int* __restrict__ src, const int* __restrict__ dst,
    const float* __restrict__ w, int* __restrict__ gcur,
    uint2* __restrict__ csr, int n_edges, int nbk, int tile, int capb) {
  __shared__ int h[NBK_MAX];
  __shared__ int cur[NBK_MAX];
  __shared__ int gb[NBK_MAX];
  const int tid = threadIdx.x;
  const int b = blockIdx.x;
  int base = b * tile;
  int lim = min(base + tile, n_edges);
  for (int k = tid; k < nbk; k += 512) h[k] = 0;
  __syncthreads();
  for (int i = base + tid; i < lim; i += 512)
    atomicAdd(&h[((unsigned)dst[i]) >> LOG_NPB], 1);
  __syncthreads();
  for (int k = tid; k < nbk; k += 512) {
    cur[k] = 0;
    int v = h[k];
    if (v) gb[k] = atomicAdd(&gcur[k], v);
  }
  __syncthreads();
  for (int i = base + tid; i < lim; i += 512) {
    unsigned d = (unsigned)dst[i];
    unsigned k = d >> LOG_NPB;
    int pos = gb[k] + atomicAdd(&cur[k], 1);
    if (capb == 0 || pos < (int)(k + 1) * capb)
      csr[pos] = make_uint2((unsigned)src[i] | ((d & (NPB - 1u)) << 20),
                            __float_as_uint(w[i]));
  }
}

// ---------------- phase 3: gather (LDS perm-sort + register accumulate) ----
// NPB=64: 1563 blocks, 16KB LDS -> ~6 blocks/CU x 4 waves (vs R8's 3),
// identical 44-VGPR 8-rows-in-flight inner loop.
__global__ __launch_bounds__(256) void gather_kernel(
    const float* __restrict__ x, const int* __restrict__ gbase,
    const int* __restrict__ gcur, const uint2* __restrict__ csr,
    float* __restrict__ out, int n_nodes, int capb,
    const int* __restrict__ src, const int* __restrict__ dst,
    const float* __restrict__ w, int n_edges) {
  __shared__ uint2 eds[CAP];            // 12 KB staged edges
  __shared__ unsigned short perm[CAP];  // 3 KB sorted order
  __shared__ int loff[NPB + 1];
  __shared__ int lcur[NPB];
  __shared__ int sh[9];

  const int b = blockIdx.x;
  const int tid = threadIdx.x;
  const int beg = capb ? b * capb : gbase[b];
  const int cnt = gcur[b] - beg;
  const int limcap = capb ? capb : CAP;   // capb <= CAP guaranteed host-side
  const int nbase = b * NPB;

  const int wv = tid >> 6;
  const int lane = tid & 63;
  const int f = lane & 31;
  const int half = lane >> 5;
  const float4* X = (const float4*)x;

  if (cnt <= limcap) {
    // stage + local hist
    if (tid < NPB) lcur[tid] = 0;
    __syncthreads();
    for (int i = tid; i < cnt; i += 256) {
      uint2 e = csr[beg + i];
      eds[i] = e;
      atomicAdd(&lcur[e.x >> 20], 1);
    }
    __syncthreads();
    // scan 64 counters -> loff, reset lcur as cursor
    {
      int v = (tid < NPB) ? lcur[tid] : 0;
      int ex = block_excl_scan(v, sh, nullptr);
      __syncthreads();
      if (tid < NPB) { loff[tid] = ex; lcur[tid] = 0; }
      if (tid == 0) loff[NPB] = cnt;
    }
    __syncthreads();
    // build perm (counting-sort placement)
    for (int i = tid; i < cnt; i += 256) {
      int dl = eds[i].x >> 20;
      int pos = loff[dl] + atomicAdd(&lcur[dl], 1);
      perm[pos] = (unsigned short)i;
    }
    __syncthreads();

    // register-accumulate per node (1 wave/node, 2 halves x unroll4)
    for (int n = wv; n < NPB; n += 4) {
      int node = nbase + n;
      if (node >= n_nodes) break;
      int jb = loff[n];
      int je = loff[n + 1];
      float4 a0 = make_float4(0.f, 0.f, 0.f, 0.f);
      float4 a1 = make_float4(0.f, 0.f, 0.f, 0.f);
      float4 a2 = make_float4(0.f, 0.f, 0.f, 0.f);
      float4 a3 = make_float4(0.f, 0.f, 0.f, 0.f);
      int j = jb + half;
      for (; j + 6 < je; j += 8) {
        uint2 e0 = eds[perm[j]];
        uint2 e1 = eds[perm[j + 2]];
        uint2 e2 = eds[perm[j + 4]];
        uint2 e3 = eds[perm[j + 6]];
        float4 v0 = X[(size_t)(e0.x & 0xFFFFFu) * 32 + f];
        float4 v1 = X[(size_t)(e1.x & 0xFFFFFu) * 32 + f];
        float4 v2 = X[(size_t)(e2.x & 0xFFFFFu) * 32 + f];
        float4 v3 = X[(size_t)(e3.x & 0xFFFFFu) * 32 + f];
        float w0 = __uint_as_float(e0.y);
        float w1 = __uint_as_float(e1.y);
        float w2 = __uint_as_float(e2.y);
        float w3 = __uint_as_float(e3.y);
        a0.x += w0 * v0.x; a0.y += w0 * v0.y; a0.z += w0 * v0.z; a0.w += w0 * v0.w;
        a1.x += w1 * v1.x; a1.y += w1 * v1.y; a1.z += w1 * v1.z; a1.w += w1 * v1.w;
        a2.x += w2 * v2.x; a2.y += w2 * v2.y; a2.z += w2 * v2.z; a2.w += w2 * v2.w;
        a3.x += w3 * v3.x; a3.y += w3 * v3.y; a3.z += w3 * v3.z; a3.w += w3 * v3.w;
      }
      for (; j < je; j += 2) {
        uint2 e0 = eds[perm[j]];
        float4 v0 = X[(size_t)(e0.x & 0xFFFFFu) * 32 + f];
        float w0 = __uint_as_float(e0.y);
        a0.x += w0 * v0.x; a0.y += w0 * v0.y; a0.z += w0 * v0.z; a0.w += w0 * v0.w;
      }
      a0.x += a1.x + a2.x + a3.x;
      a0.y += a1.y + a2.y + a3.y;
      a0.z += a1.z + a2.z + a3.z;
      a0.w += a1.w + a2.w + a3.w;
      a0.x += __shfl_xor(a0.x, 32, 64);
      a0.y += __shfl_xor(a0.y, 32, 64);
      a0.z += __shfl_xor(a0.z, 32, 64);
      a0.w += __shfl_xor(a0.w, 32, 64);
      if (half == 0) {
        v4f val = {a0.x, a0.y, a0.z, a0.w};
        __builtin_nontemporal_store(val, (v4f*)out + (size_t)node * 32 + f);
      }
    }
  } else {
    // safety net (statistically unreachable; also covers segment overflow):
    // scan the RAW edge list for this bucket's nodes.
    for (int n = wv; n < NPB; n += 4) {
      int node = nbase + n;
      if (node >= n_nodes) break;
      float4 a0 = make_float4(0.f, 0.f, 0.f, 0.f);
      for (int j = half; j < n_edges; j += 2) {
        if (dst[j] == node) {
          float4 v = X[(size_t)src[j] * 32 + f];
          float wt = w[j];
          a0.x += wt * v.x; a0.y += wt * v.y; a0.z += wt * v.z; a0.w += wt * v.w;
        }
      }
      a0.x += __shfl_xor(a0.x, 32, 64);
      a0.y += __shfl_xor(a0.y, 32, 64);
      a0.z += __shfl_xor(a0.z, 32, 64);
      a0.w += __shfl_xor(a0.w, 32, 64);
      if (half == 0) {
        v4f val = {a0.x, a0.y, a0.z, a0.w};
        __builtin_nontemporal_store(val, (v4f*)out + (size_t)node * 32 + f);
      }
    }
  }
}

extern "C" void kernel_launch(void* const* d_in, const int* in_sizes, int n_in,
                              void* d_out, int out_size, void* d_ws, size_t ws_size,
                              hipStream_t stream) {
  const float* x  = (const float*)d_in[0];
  const float* w  = (const float*)d_in[1];
  const int* eidx = (const int*)d_in[2];

  int n_edges = in_sizes[1];           // E
  int n_nodes = out_size / D_FEAT;     // N
  const int* src = eidx;
  const int* dst = eidx + n_edges;
  float* out = (float*)d_out;

  if (n_edges <= 0) {
    hipMemsetAsync(d_out, 0, (size_t)out_size * sizeof(float), stream);
    return;
  }

  const int nbk = (n_nodes + NPB - 1) / NPB;       // buckets (1563 @100K)
  const int stile = (n_edges + SCB - 1) / SCB;     // edges per scatter block
  const int htile = (n_edges + HBLK - 1) / HBLK;   // edges per hist block

  // ws layout (ints): gtot[2048] | gcur[2048] | done[4] | gbase[2052] | csr
  const size_t ctrl_ints = (size_t)NBK_MAX + NBK_MAX + 4 + (NBK_MAX + 4);
  const size_t ctrl_bytes = ctrl_ints * 4;
  long long slots_avail =
      ((long long)ws_size - (long long)ctrl_bytes) / 8;

  // segment sizing: capb slots per bucket at fixed offsets
  long long mean = n_edges / (nbk > 0 ? nbk : 1);
  int capb_min = (int)(mean + 7.0 * sqrt((double)(mean > 0 ? mean : 1)) + 32);
  int capb = 0;
  if (nbk > 0 && slots_avail > 0) {
    long long c = slots_avail / nbk;
    if (c > CAP) c = CAP;
    capb = (int)(c & ~7LL);              // 64B-aligned segment starts
  }
  bool seg_ok = (capb >= capb_min);
  bool exact_ok = (slots_avail >= (long long)n_edges);

  if ((!seg_ok && !exact_ok) || nbk > NBK_MAX || n_nodes >= (1 << 20)) {
    hipMemsetAsync(d_out, 0, (size_t)out_size * sizeof(float), stream);
    long long total_threads = (long long)n_edges * 32;
    long long grid = (total_threads + 255) / 256;
    scatter_atomic_kernel<<<(dim3)(unsigned)grid, 256, 0, stream>>>(
        x, w, src, dst, out, n_edges);
    return;
  }

  int* gtot = (int*)d_ws;                   // 2048
  int* gcur = gtot + NBK_MAX;               // 2048
  int* done = gcur + NBK_MAX;               // 4
  int* gbase = done + 4;                    // 2052 (nbk+1 used)
  uint2* csr = (uint2*)(gbase + NBK_MAX + 4);

  if (seg_ok) {
    // 3 dispatches: init -> scatter -> gather (no hist, no scan, no memset)
    init_seg_kernel<<<(nbk + 255) / 256, 256, 0, stream>>>(gcur, nbk, capb);
    scatter_kernel<<<SCB, 512, 0, stream>>>(src, dst, w, gcur, csr,
                                            n_edges, nbk, stile, capb);
    gather_kernel<<<nbk, 256, 0, stream>>>(x, gbase, gcur, csr, out, n_nodes,
                                           capb, src, dst, w, n_edges);
  } else {
    // exact-CSR path: memset -> hist(+prefix) -> scatter -> gather
    hipMemsetAsync(gtot, 0, (size_t)(NBK_MAX * 2 + 4) * sizeof(int), stream);
    hist_kernel<<<HBLK, 512, 0, stream>>>(dst, gtot, gcur, gbase, done,
                                          n_edges, nbk, htile);
    scatter_kernel<<<SCB, 512, 0, stream>>>(src, dst, w, gcur, csr,
                                            n_edges, nbk, stile, 0);
    gather_kernel<<<nbk, 256, 0, stream>>>(x, gbase, gcur, csr, out, n_nodes,
                                           0, src, dst, w, n_edges);
  }
}